// Round 4
// baseline (288.612 us; speedup 1.0000x reference)
//
#include <hip/hip_runtime.h>
#include <math.h>

#define T_SEQ 34
#define VOCAB 14
#define NE 476          // 34*14 distinct (t, token) states
#define SEQS 64         // sequences per block
#define BLK 576         // 9 waves: lane=seq, wave=t-group (uniform T0 per wave)
#define NBLK 1024       // 65536/64
#define OFFP 35         // padded int stride for offt (2-way banks = free)
#define LDS_BYTES 61184 // max(tables 43232, ostage 32*239*8 = 61184)

__device__ __forceinline__ void layernorm6(const float* x, const float* g,
                                           const float* bt, float* o) {
    float mu = (x[0] + x[1] + x[2] + x[3] + x[4] + x[5]) * (1.0f / 6.0f);
    float var = 0.0f;
#pragma unroll
    for (int i = 0; i < 6; ++i) { float d = x[i] - mu; var += d * d; }
    var *= (1.0f / 6.0f);
    float rs = rsqrtf(var + 1e-5f);
#pragma unroll
    for (int i = 0; i < 6; ++i) o[i] = (x[i] - mu) * rs * g[i] + bt[i];
}

__global__ __launch_bounds__(BLK, 5) void fused_tf_kernel(
    const int* __restrict__ idx,
    const float* __restrict__ tok_emb,
    const float* __restrict__ pos_enc,
    const float* __restrict__ wq,
    const float* __restrict__ wk,
    const float* __restrict__ wv,
    const float* __restrict__ wo,
    const float* __restrict__ ln1_g, const float* __restrict__ ln1_b,
    const float* __restrict__ ln2_g, const float* __restrict__ ln2_b,
    const float* __restrict__ w1,   const float* __restrict__ b1,
    const float* __restrict__ w2,   const float* __restrict__ b2,
    const float* __restrict__ lnf_g, const float* __restrict__ lnf_b,
    const float* __restrict__ w_head,
    float* __restrict__ out)
{
    // Dynamic LDS union: [tables] during attention, [output stage] afterwards.
    extern __shared__ __align__(16) unsigned char uS[];
    float4* kvA  = (float4*)(uS + 0);      // k0x k0y k0z k1x (k scaled 1/sqrt3)
    float4* kvB  = (float4*)(uS + 7616);   // k1y k1z v0x v0y
    float4* kvC  = (float4*)(uS + 15232);  // v0z v1x v1y v1z
    float4* qA   = (float4*)(uS + 22848);  // q0x q0y q0z q1x
    float2* qB   = (float2*)(uS + 30464);  // q1y q1z
    int*    offt = (int*)  (uS + 34272);   // 64*35 ints -> ends 43232
    float2* o2   = (float2*)uS;            // stage: [sL]*239 + t*7 + j (pad->2-way banks)

    __shared__ float temb[VOCAB * 3];      // outside the union: alive in epilogue
    __shared__ float penc[T_SEQ * 3];

    const int tid = threadIdx.x;

    // ---- stage idx -> table indices (coalesced) ----
    for (int i = tid; i < SEQS * T_SEQ; i += BLK) {
        const int sq = i / T_SEQ;
        const int s  = i - sq * T_SEQ;
        offt[sq * OFFP + s] = s * VOCAB + idx[(size_t)blockIdx.x * (SEQS * T_SEQ) + i];
    }
    if (tid < VOCAB * 3) temb[tid] = tok_emb[tid];
    if (tid < T_SEQ * 3) penc[tid] = pos_enc[tid];

    // ---- build 476-state tables ----
    if (tid < NE) {
        const int t = tid / VOCAB;
        const int v = tid - t * VOCAB;
        float x[6];
#pragma unroll
        for (int i = 0; i < 3; ++i) x[i] = tok_emb[v * 3 + i];
#pragma unroll
        for (int i = 0; i < 3; ++i) x[3 + i] = pos_enc[t * 3 + i];
        float xl[6];
        layernorm6(x, ln1_g, ln1_b, xl);
        const float kscale = 0.57735026918962576f;  // 1/sqrt(HEAD_DIM)
        float qv[6], kv6[6], vv[6];
#pragma unroll
        for (int j = 0; j < 6; ++j) {
            qv[j]  =  xl[3] * wq[j] + xl[4] * wq[6 + j] + xl[5] * wq[12 + j];
            kv6[j] = (xl[3] * wk[j] + xl[4] * wk[6 + j] + xl[5] * wk[12 + j]) * kscale;
            vv[j]  =  xl[0] * wv[j] + xl[1] * wv[6 + j] + xl[2] * wv[12 + j];
        }
        kvA[tid] = make_float4(kv6[0], kv6[1], kv6[2], kv6[3]);
        kvB[tid] = make_float4(kv6[4], kv6[5], vv[0], vv[1]);
        kvC[tid] = make_float4(vv[2], vv[3], vv[4], vv[5]);
        qA[tid]  = make_float4(qv[0], qv[1], qv[2], qv[3]);
        qB[tid]  = make_float2(qv[4], qv[5]);
    }
    __syncthreads();

    const int seq = tid & 63;                 // lane = sequence -> uniform waves
    const int grp = tid >> 6;                 // wave = t-group
    const int T0  = (grp == 8) ? 30 : (grp << 2);  // grp8 recomputes t=30,31 (benign)
    const int* myoff = &offt[seq * OFFP];

    // ---- q fragments + own tokens ----
    float q[4][6]; int tokR[4];
#pragma unroll
    for (int i = 0; i < 4; ++i) {
        const int e = myoff[T0 + i];
        tokR[i] = e - VOCAB * (T0 + i);
        const float4 a = qA[e]; const float2 bb = qB[e];
        q[i][0] = a.x; q[i][1] = a.y; q[i][2] = a.z;
        q[i][3] = a.w; q[i][4] = bb.x; q[i][5] = bb.y;
    }
    float den0[4], den1[4], acc[4][6];
#pragma unroll
    for (int i = 0; i < 4; ++i) {
        den0[i] = 0.f; den1[i] = 0.f;
#pragma unroll
        for (int j = 0; j < 6; ++j) acc[i][j] = 0.f;
    }

    auto body = [&](int e, int imin) {
        const float4 ea = kvA[e]; const float4 eb = kvB[e]; const float4 ec = kvC[e];
#pragma unroll
        for (int i = 0; i < 4; ++i) {
            if (i >= imin) {
                const float s0 = q[i][0] * ea.x + q[i][1] * ea.y + q[i][2] * ea.z;
                const float s1 = q[i][3] * ea.w + q[i][4] * eb.x + q[i][5] * eb.y;
                const float p0 = __expf(s0);
                const float p1 = __expf(s1);
                den0[i] += p0; den1[i] += p1;
                acc[i][0] += p0 * eb.z; acc[i][1] += p0 * eb.w; acc[i][2] += p0 * ec.x;
                acc[i][3] += p1 * ec.y; acc[i][4] += p1 * ec.z; acc[i][5] += p1 * ec.w;
            }
        }
    };
    for (int s = 0; s < T0; ++s) body(myoff[s], 0);      // shared prefix
#pragma unroll
    for (int j = 0; j < 4; ++j) body(myoff[T0 + j], j);  // causal tail

    // ---- epilogue + staged write-out, 32 sequences per chunk ----
    for (int c = 0; c < 2; ++c) {
        __syncthreads();   // tables dead (c=0) / previous copy done (c=1)
        if ((seq >> 5) == c) {
            const int sL = seq & 31;
#pragma unroll
            for (int i = 0; i < 4; ++i) {
                const int t = T0 + i;
                const float inv0 = __builtin_amdgcn_rcpf(den0[i]);
                const float inv1 = __builtin_amdgcn_rcpf(den1[i]);
                float ao[6];
#pragma unroll
                for (int d = 0; d < 3; ++d) {
                    ao[d]     = acc[i][d]     * inv0;
                    ao[3 + d] = acc[i][3 + d] * inv1;
                }
                float x[6];
#pragma unroll
                for (int k = 0; k < 3; ++k) {
                    x[k]     = temb[tokR[i] * 3 + k];
                    x[3 + k] = penc[t * 3 + k];
                }
                float x2[6];
#pragma unroll
                for (int j = 0; j < 6; ++j) {
                    float s = x[j];
#pragma unroll
                    for (int k = 0; k < 6; ++k) s += ao[k] * wo[k * 6 + j];
                    x2[j] = s;
                }
                float h[6];
                layernorm6(x2, ln2_g, ln2_b, h);
                float f[6];
#pragma unroll
                for (int j = 0; j < 6; ++j) {
                    float s = b1[j];
#pragma unroll
                    for (int k = 0; k < 6; ++k) s += h[k] * w1[k * 6 + j];
                    f[j] = 0.5f * s * (1.0f + erff(s * 0.70710678118654752f));
                }
                float x3[6];
#pragma unroll
                for (int j = 0; j < 6; ++j) {
                    float s = x2[j] + b2[j];
#pragma unroll
                    for (int k = 0; k < 6; ++k) s += f[k] * w2[k * 6 + j];
                    x3[j] = s;
                }
                float xo[6];
                layernorm6(x3, lnf_g, lnf_b, xo);

                float2* orow = &o2[sL * 239 + t * 7];
#pragma unroll
                for (int jj = 0; jj < 7; ++jj) {
                    float o0 = 0.f, o1 = 0.f;
#pragma unroll
                    for (int k = 0; k < 6; ++k) {
                        o0 += xo[k] * w_head[k * 14 + 2 * jj];
                        o1 += xo[k] * w_head[k * 14 + 2 * jj + 1];
                    }
                    orow[jj] = make_float2(o0, o1);
                }
            }
        }
        __syncthreads();   // stage complete
        // stream 60928 B to global: consecutive float2 -> full-line coalesced
        float2* dst = (float2*)(out + ((size_t)blockIdx.x * SEQS + c * 32) * (T_SEQ * 14));
        for (int i = tid; i < 32 * T_SEQ * 7; i += BLK) {
            const unsigned sq = (unsigned)i / 238u;   // magic-mul div
            dst[i] = o2[i + sq];                      // lds idx = sq*239 + rem
        }
    }
}

extern "C" void kernel_launch(void* const* d_in, const int* in_sizes, int n_in,
                              void* d_out, int out_size, void* d_ws, size_t ws_size,
                              hipStream_t stream) {
    const int*   idx     = (const int*)d_in[0];
    const float* tok_emb = (const float*)d_in[1];
    const float* pos_enc = (const float*)d_in[2];
    const float* wq      = (const float*)d_in[3];
    const float* wk      = (const float*)d_in[4];
    const float* wv      = (const float*)d_in[5];
    const float* wo      = (const float*)d_in[6];
    const float* ln1_g   = (const float*)d_in[7];
    const float* ln1_b   = (const float*)d_in[8];
    const float* ln2_g   = (const float*)d_in[9];
    const float* ln2_b   = (const float*)d_in[10];
    const float* w1      = (const float*)d_in[11];
    const float* b1      = (const float*)d_in[12];
    const float* w2      = (const float*)d_in[13];
    const float* b2      = (const float*)d_in[14];
    const float* lnf_g   = (const float*)d_in[15];
    const float* lnf_b   = (const float*)d_in[16];
    const float* w_head  = (const float*)d_in[17];
    float* out = (float*)d_out;

    hipLaunchKernelGGL(fused_tf_kernel, dim3(NBLK), dim3(BLK), LDS_BYTES, stream,
                       idx, tok_emb, pos_enc, wq, wk, wv, wo,
                       ln1_g, ln1_b, ln2_g, ln2_b, w1, b1, w2, b2,
                       lnf_g, lnf_b, w_head, out);
}